// Round 6
// baseline (575.761 us; speedup 1.0000x reference)
//
#include <hip/hip_runtime.h>

// Problem constants (from reference setup_inputs)
constexpr int kB = 256;
constexpr int kT = 2048;
constexpr int kI = 32;
constexpr int kH = 64;
constexpr int kO = 16;
constexpr int kPadL = 2;
constexpr int kPadR = 3;
constexpr int kTp = kT + kPadL + kPadR;  // 2053
constexpr int kCT = 64;                  // timesteps per producer chunk
constexpr int kNC = kT / kCT;            // 32 chunks

constexpr float kS = 1.4426950408889634f;  // log2(e), folded into weights

// Dynamic-LDS byte layout:
//   [0, 128)            rbuf : 64 x f16 broadcast of r
//   [128, 128+2*16384)  xinbuf: 2 x (64 t x 64 h) f32, double-buffered
//   [32896, 33152)      aggbuf: 64 x f32 (epilogue)
constexpr unsigned kRbufOff  = 0;
constexpr unsigned kXinOff   = 128;
constexpr unsigned kXinBytes = kCT * kH * 4;            // 16384
constexpr unsigned kAggOff   = kXinOff + 2 * kXinBytes; // 32896
constexpr unsigned kSmemBytes = kAggOff + kH * 4;       // 33152

typedef float    v2f __attribute__((ext_vector_type(2)));
typedef _Float16 v2h __attribute__((ext_vector_type(2)));
typedef unsigned v4u __attribute__((ext_vector_type(4)));

extern __shared__ char smem[];

__device__ __forceinline__ void pk_fma(v2f& d, v2f a, v2f b) {
  asm("v_pk_fma_f32 %0, %1, %2, %0" : "+v"(d) : "v"(a), "v"(b));
}

__device__ __forceinline__ v2h as_h2(unsigned u) {
  return __builtin_bit_cast(v2h, u);
}

__device__ __forceinline__ float dot2(v2h a, v2h b, float c) {
#if __has_builtin(__builtin_amdgcn_fdot2)
  return __builtin_amdgcn_fdot2(a, b, c, false);
#else
  return fmaf((float)a.x, (float)b.x, fmaf((float)a.y, (float)b.y, c));
#endif
}

__device__ __forceinline__ float exp2_fast(float x) {
#if __has_builtin(__builtin_amdgcn_exp2f)
  return __builtin_amdgcn_exp2f(x);
#else
  return exp2f(x);
#endif
}

// Issue-only blobs: write r, issue all broadcast reads (+ xin prefetch), but
// do NOT wait. Staged s_waitcnt blobs below release each quad as its data
// returns, so dot issue overlaps the read-return pipeline.
#define STEP_ISSUE_MAIN(q0, q1, q2, q3, q4, q5, q6, q7, xn, rv, xaddr) \
  asm volatile(                                                        \
      "ds_write_b16 %9, %10\n\t"                                       \
      "ds_read_b128 %0, %11 offset:0\n\t"                              \
      "ds_read_b128 %1, %11 offset:16\n\t"                             \
      "ds_read_b128 %2, %11 offset:32\n\t"                             \
      "ds_read_b128 %3, %11 offset:48\n\t"                             \
      "ds_read_b128 %4, %11 offset:64\n\t"                             \
      "ds_read_b128 %5, %11 offset:80\n\t"                             \
      "ds_read_b128 %6, %11 offset:96\n\t"                             \
      "ds_read_b128 %7, %11 offset:112\n\t"                            \
      "ds_read_b32 %8, %12"                                            \
      : "=v"(q0), "=v"(q1), "=v"(q2), "=v"(q3),                        \
        "=v"(q4), "=v"(q5), "=v"(q6), "=v"(q7), "=v"(xn)               \
      : "v"(raddr), "v"(rv), "v"(rbase), "v"(xaddr))

#define STEP_ISSUE_NOX(q0, q1, q2, q3, q4, q5, q6, q7, rv)             \
  asm volatile(                                                        \
      "ds_write_b16 %8, %9\n\t"                                        \
      "ds_read_b128 %0, %10 offset:0\n\t"                              \
      "ds_read_b128 %1, %10 offset:16\n\t"                             \
      "ds_read_b128 %2, %10 offset:32\n\t"                             \
      "ds_read_b128 %3, %10 offset:48\n\t"                             \
      "ds_read_b128 %4, %10 offset:64\n\t"                             \
      "ds_read_b128 %5, %10 offset:80\n\t"                             \
      "ds_read_b128 %6, %10 offset:96\n\t"                             \
      "ds_read_b128 %7, %10 offset:112"                                \
      : "=v"(q0), "=v"(q1), "=v"(q2), "=v"(q3),                        \
        "=v"(q4), "=v"(q5), "=v"(q6), "=v"(q7)                         \
      : "v"(raddr), "v"(rv), "v"(rbase))

// Wait until quad Q's data has returned (N = remaining outstanding DS ops).
// "+v"(Q) makes the dots on Q order after this wait.
#define WAITQ(N, Q) asm volatile("s_waitcnt lgkmcnt(" N ")" : "+v"(Q))

__global__ __launch_bounds__(128) void rnn_fused(
    const float* __restrict__ x,
    const float* __restrict__ W_ih,
    const float* __restrict__ W_hh,
    const float* __restrict__ b_ih,
    const float* __restrict__ b_hh,
    const float* __restrict__ W_fc,
    const float* __restrict__ b_fc,
    float* __restrict__ out)
{
  const int b = blockIdx.x;
  const int lane = threadIdx.x & 63;   // hidden unit index
  const int wave = threadIdx.x >> 6;

  // bias' = 2*kS*(b_ih + b_hh + rowsum(W_hh row lane))
  float rowsum = 0.0f;
#pragma unroll
  for (int j = 0; j < kH; j += 4) {
    float4 v = *(const float4*)(W_hh + lane * kH + j);
    rowsum += (v.x + v.y) + (v.z + v.w);
  }
  const float bias2 = 2.0f * kS * (b_ih[lane] + b_hh[lane] + rowsum);

  if (wave == 1) {
    // ================= producer =================
    v2f wi2[kI / 2];  // 2*kS*W_ih[lane][i]
#pragma unroll
    for (int i = 0; i < kI; i += 4) {
      float4 v = *(const float4*)(W_ih + lane * kI + i);
      wi2[i / 2 + 0] = v2f{2.0f * kS * v.x, 2.0f * kS * v.y};
      wi2[i / 2 + 1] = v2f{2.0f * kS * v.z, 2.0f * kS * v.w};
    }
    const float* xb = x + (size_t)b * kT * kI;

    auto fill = [&](int c, int buf) {
      const float* src = xb + (size_t)c * kCT * kI;
      float* dst = (float*)(smem + kXinOff + buf * kXinBytes);
#pragma unroll 2
      for (int t = 0; t < kCT; ++t) {
        const float4* row = (const float4*)(src + t * kI);  // broadcast loads
        v2f a0 = v2f{0.0f, 0.0f}, a1 = v2f{0.0f, 0.0f};
#pragma unroll
        for (int i2 = 0; i2 < 8; ++i2) {
          float4 v = row[i2];
          pk_fma(a0, wi2[2 * i2 + 0], v2f{v.x, v.y});
          pk_fma(a1, wi2[2 * i2 + 1], v2f{v.z, v.w});
        }
        dst[t * kH + lane] = bias2 + ((a0.x + a0.y) + (a1.x + a1.y));
      }
    };

    fill(0, 0);
    __syncthreads();  // buffer 0 ready
    for (int c = 0; c < kNC; ++c) {
      if (c + 1 < kNC) fill(c + 1, (c + 1) & 1);
      __syncthreads();  // end of chunk c
    }
    return;
  }

  // ================= consumer (wave 0) =================
  v2h wh[kH / 2];  // -4*kS*W_hh[lane][j] as fp16 pairs
#pragma unroll
  for (int j = 0; j < kH; j += 2) {
    float w0 = W_hh[lane * kH + j + 0];
    float w1 = W_hh[lane * kH + j + 1];
    wh[j / 2] = v2h{(_Float16)(-4.0f * kS * w0), (_Float16)(-4.0f * kS * w1)};
  }

  const unsigned raddr = kRbufOff + (unsigned)lane * 2u;  // this lane's r slot
  unsigned rbase = kRbufOff;                              // broadcast base (0)

  float rsum = 0.0f;
  unsigned rv = (unsigned)__builtin_bit_cast(unsigned short, (_Float16)0.5f);

#define DOTS4(Q, BASE)                         \
  za = dot2(as_h2((Q).x), wh[(BASE) + 0], za); \
  zb = dot2(as_h2((Q).y), wh[(BASE) + 1], zb); \
  zc = dot2(as_h2((Q).z), wh[(BASE) + 2], zc); \
  zd = dot2(as_h2((Q).w), wh[(BASE) + 3], zd)

  auto finish = [&](float za, float zb, float zc, float zd) {
    float z2 = (za + zb) + (zc + zd);   // = 2*z*log2e
    float t = exp2_fast(z2);            // e^{2z}; inf -> r = 0 (graceful)
    float r = __builtin_amdgcn_rcpf(1.0f + t);
    rsum += r;
    rv = (unsigned)__builtin_bit_cast(unsigned short, (_Float16)r);
  };

  auto pad_step = [&]() {
    v4u q0, q1, q2, q3, q4, q5, q6, q7;
    STEP_ISSUE_NOX(q0, q1, q2, q3, q4, q5, q6, q7, rv);
    float za = bias2, zb = 0.0f, zc = 0.0f, zd = 0.0f;
    WAITQ("7", q0); DOTS4(q0, 0);
    WAITQ("6", q1); DOTS4(q1, 4);
    WAITQ("5", q2); DOTS4(q2, 8);
    WAITQ("4", q3); DOTS4(q3, 12);
    WAITQ("3", q4); DOTS4(q4, 16);
    WAITQ("2", q5); DOTS4(q5, 20);
    WAITQ("1", q6); DOTS4(q6, 24);
    WAITQ("0", q7); DOTS4(q7, 28);
    finish(za, zb, zc, zd);
  };

  // left padding (runs while producer fills buffer 0)
  pad_step();
  pad_step();
  __syncthreads();  // buffer 0 ready

  for (int c = 0; c < kNC; ++c) {
    const unsigned xbase = kXinOff + (unsigned)(c & 1) * kXinBytes +
                           (unsigned)lane * 4u;
    // prime this chunk's first xin (post-barrier: no race with producer)
    float xc;
    asm volatile("ds_read_b32 %0, %1\n\ts_waitcnt lgkmcnt(0)"
                 : "=v"(xc) : "v"(xbase));
#pragma unroll 7
    for (int t = 0; t < kCT - 1; ++t) {
      v4u q0, q1, q2, q3, q4, q5, q6, q7;
      float xn;
      const unsigned xaddr = xbase + (unsigned)(t + 1) * (kH * 4u);
      STEP_ISSUE_MAIN(q0, q1, q2, q3, q4, q5, q6, q7, xn, rv, xaddr);
      float za = xc, zb = 0.0f, zc = 0.0f, zd = 0.0f;
      WAITQ("8", q0); DOTS4(q0, 0);
      WAITQ("7", q1); DOTS4(q1, 4);
      WAITQ("6", q2); DOTS4(q2, 8);
      WAITQ("5", q3); DOTS4(q3, 12);
      WAITQ("4", q4); DOTS4(q4, 16);
      WAITQ("3", q5); DOTS4(q5, 20);
      WAITQ("2", q6); DOTS4(q6, 24);
      WAITQ("1", q7); DOTS4(q7, 28);
      asm volatile("s_waitcnt lgkmcnt(0)" : "+v"(xn));  // xin prefetch done
      finish(za, zb, zc, zd);
      xc = xn;
    }
    {  // step kCT-1: uses xc, no prefetch across the barrier
      v4u q0, q1, q2, q3, q4, q5, q6, q7;
      STEP_ISSUE_NOX(q0, q1, q2, q3, q4, q5, q6, q7, rv);
      float za = xc, zb = 0.0f, zc = 0.0f, zd = 0.0f;
      WAITQ("7", q0); DOTS4(q0, 0);
      WAITQ("6", q1); DOTS4(q1, 4);
      WAITQ("5", q2); DOTS4(q2, 8);
      WAITQ("4", q3); DOTS4(q3, 12);
      WAITQ("3", q4); DOTS4(q4, 16);
      WAITQ("2", q5); DOTS4(q5, 20);
      WAITQ("1", q6); DOTS4(q6, 24);
      WAITQ("0", q7); DOTS4(q7, 28);
      finish(za, zb, zc, zd);
    }
    __syncthreads();  // done with this buffer
  }

  // right padding
  pad_step();
  pad_step();
  pad_step();

  // ---- epilogue: mean over Tp, FC (16x64) + ReLU (single wave) ----
  float* aggbuf = (float*)(smem + kAggOff);
  aggbuf[lane] = 1.0f - 2.0f * rsum * (1.0f / (float)kTp);
  if (lane < kO) {
    float acc = b_fc[lane];
    const float* wf = W_fc + lane * kH;
#pragma unroll
    for (int j = 0; j < kH; ++j)
      acc = fmaf(wf[j], aggbuf[j], acc);
    out[b * kO + lane] = fmaxf(acc, 0.0f);
  }
#undef DOTS4
}

extern "C" void kernel_launch(void* const* d_in, const int* in_sizes, int n_in,
                              void* d_out, int out_size, void* d_ws, size_t ws_size,
                              hipStream_t stream) {
  const float* x    = (const float*)d_in[0];
  const float* W_ih = (const float*)d_in[1];
  const float* W_hh = (const float*)d_in[2];
  const float* b_ih = (const float*)d_in[3];
  const float* b_hh = (const float*)d_in[4];
  const float* W_fc = (const float*)d_in[5];
  const float* b_fc = (const float*)d_in[6];
  float* out = (float*)d_out;

  rnn_fused<<<dim3(kB), dim3(128), kSmemBytes, stream>>>(
      x, W_ih, W_hh, b_ih, b_hh, W_fc, b_fc, out);
}